// Round 9
// baseline (1048.173 us; speedup 1.0000x reference)
//
#include <hip/hip_runtime.h>
#include <hip/hip_cooperative_groups.h>
#include <cstdint>

namespace cg = cooperative_groups;

typedef long long ll;
typedef unsigned long long ull;

constexpr int N_ = 1024;           // atoms (fixed by problem)
constexpr int BLK = 256;
constexpr int NB  = 1024;          // blocks = 4/CU exact (cooperative co-residency)
constexpr int RNDS = 54;           // classify rounds per block
constexpr int CHUNK = BLK * RNDS;  // 13824 pairs per block = 216 mask words
constexpr int WPW = 54;            // mask words per wave (invalid writer)
constexpr int Q4 = 27648;          // float4 zero-fill quota per block (>= T/NB)

__device__ __forceinline__ ll rowstart(int i) {
  return (ll)i * (2 * N_ - 1 - i) / 2;
}

// invert triu(N,k=1) linear index -> (i,j)
__device__ __forceinline__ void decode_center(ll p, int& i, int& j) {
  double disc = (double)(2 * N_ - 1) * (double)(2 * N_ - 1) - 8.0 * (double)p;
  int ii = (int)(((double)(2 * N_ - 1) - sqrt(disc)) * 0.5);
  if (ii < 0) ii = 0;
  if (ii > N_ - 2) ii = N_ - 2;
  while (rowstart(ii) > p) --ii;
  while (rowstart(ii + 1) <= p) ++ii;
  i = ii;
  j = ii + 1 + (int)(p - rowstart(ii));
}

// ---------------- single cooperative kernel ----------------
// phase 0: zero atomic counters (replaces memset dispatch)
// phase 1: classify pairs -> bitmask + counts, fused float4 zero-fill of out[2T,6T)
// phase 2: invalid idx writer for this block's chunk (mask words L1/L2-warm),
//          then valid scatter for atom a = blockIdx (ssv reused from phase 1).
__global__ __launch_bounds__(BLK, 4) void k_all(
    const float* __restrict__ pos, const float* __restrict__ box,
    const int* __restrict__ shifts, int S, ll Pc, ll P, ll T,
    float4* __restrict__ zp, ull* __restrict__ mask64,
    unsigned* __restrict__ blockCount, unsigned* __restrict__ cnt,
    float* __restrict__ out)
{
  cg::grid_group grid = cg::this_grid();
  __shared__ float4 sp[N_];
  __shared__ float ssv[16][3];
  __shared__ unsigned wcnt4[4];
  __shared__ unsigned part[BLK];
  __shared__ unsigned res[8];
  __shared__ unsigned wq[4];
  unsigned* cntA = cnt;
  unsigned* cntB = cnt + N_;
  unsigned* cntC = cnt + 2 * N_;
  unsigned* cntD = cnt + 3 * N_;
  int tid = threadIdx.x, lane = tid & 63, wave = tid >> 6;
  int b = (int)blockIdx.x;
  float* oi = out;
  float* oj = out + T;
  float* oo = out + 2 * T;
  float* ov = out + 5 * T;
  ull lt = (1ull << lane) - 1ull;

  // ===== phase 0: zero cnt (4096 entries across 16 blocks) =====
  if (b < 16) cnt[(b << 8) + tid] = 0u;
  __threadfence();
  grid.sync();

  // ===== phase 1: classify + fused fill =====
  for (int a = tid; a < N_; a += BLK)
    sp[a] = make_float4(pos[3 * a + 0], pos[3 * a + 1], pos[3 * a + 2], 0.f);
  if (tid < S) {
    for (int k = 0; k < 3; ++k) {
      float acc = 0.f;
      for (int m = 0; m < 3; ++m)
        acc = __fadd_rn(acc, __fmul_rn((float)shifts[3 * tid + m], box[3 * m + k]));
      ssv[tid][k] = acc;
    }
  }
  __syncthreads();
  {
    ll chunk = (ll)b * CHUNK;
    ll fillBase = (ll)b * Q4 + tid;
    const float4 z4 = make_float4(0.f, 0.f, 0.f, 0.f);
    unsigned wrun = 0;
    for (int r = 0; r < RNDS; ++r) {
      ll p0 = chunk + r * BLK + wave * 64;
      bool inr = (p0 < P);
      bool valid = false;
      if (inr) {
        ll p = p0 + lane;
        int i, j;
        float svx = 0.f, svy = 0.f, svz = 0.f;
        if (p < Pc) {
          decode_center(p, i, j);
        } else {
          ll q = p - Pc;
          int s = (int)(q >> 20);
          i = (int)((q >> 10) & (N_ - 1));
          j = (int)(q & (N_ - 1));
          svx = ssv[s][0]; svy = ssv[s][1]; svz = ssv[s][2];
        }
        float4 pi = sp[i], pj = sp[j];
        // strict IEEE order to match reference: (pi-pj)+sv, (x^2+y^2)+z^2, < 25.
        // d2 < 25.0f  <=>  rn(sqrt(d2)) < 5.0f (sqrtf correctly rounded, monotone)
        float dx = __fadd_rn(__fsub_rn(pi.x, pj.x), svx);
        float dy = __fadd_rn(__fsub_rn(pi.y, pj.y), svy);
        float dz = __fadd_rn(__fsub_rn(pi.z, pj.z), svz);
        float d2 = __fadd_rn(__fadd_rn(__fmul_rn(dx, dx), __fmul_rn(dy, dy)),
                             __fmul_rn(dz, dz));
        valid = (d2 < 25.0f);
        if (valid) {
          if (p < Pc) { atomicAdd(&cntA[i], 1u); atomicAdd(&cntC[j], 1u); }
          else        { atomicAdd(&cntB[i], 1u); atomicAdd(&cntD[j], 1u); }
        }
      }
      ull bal = __ballot(valid);
      if (lane == 0) {
        if (inr) mask64[p0 >> 6] = bal;
        wrun += (unsigned)__popcll(bal);
      }
      // fused zero-fill: 2 float4 per thread per round, contiguous per block
      ll f0 = fillBase + ((ll)r << 9);
      if (f0 < T) zp[f0] = z4;
      ll f1 = f0 + BLK;
      if (f1 < T) zp[f1] = z4;
    }
    if (lane == 0) wcnt4[wave] = wrun;
    __syncthreads();
    if (tid == 0)
      blockCount[b] = wcnt4[0] + wcnt4[1] + wcnt4[2] + wcnt4[3];
  }
  __threadfence();
  grid.sync();

  // ===== phase 2a: invalid idx writer for chunk b =====
  {
    unsigned mysum = 0;
    int e0 = 4 * tid;
#pragma unroll
    for (int e = 0; e < 4; ++e) mysum += blockCount[e0 + e];   // 256*4 = NB exact
    part[tid] = mysum;
    for (int off = 1; off < BLK; off <<= 1) {
      __syncthreads();
      unsigned x = (tid >= off) ? part[tid - off] : 0u;
      __syncthreads();
      part[tid] += x;
    }
    __syncthreads();
    if (tid == 0) {
      int q = b >> 2;
      unsigned excl = (q > 0) ? part[q - 1] : 0u;
      for (int m = 4 * q; m < b; ++m) excl += blockCount[m];
      res[0] = excl;            // valid count before this block
      res[1] = part[BLK - 1];   // Vp = total valid pair count
    }
    // per-wave span: 54 mask words, one per lane (lane<54) — warm in L1/L2
    ll Wtot = P >> 6;           // P is word-aligned
    ll w0 = (ll)b * 216 + (ll)wave * WPW;
    ll widx = w0 + lane;
    ull myword = 0ull;
    if (lane < WPW) myword = (widx < Wtot) ? mask64[widx] : ~0ull; // fakes: no writes
    unsigned ws = (unsigned)__popcll(myword);
    for (int d = 1; d < 64; d <<= 1) ws += __shfl_xor(ws, d);
    if (lane == 0) wq[wave] = ws;
    __syncthreads();
    unsigned gv = res[0];
    for (int w2 = 0; w2 < 4; ++w2) if (w2 < wave) gv += wq[w2];
    unsigned Vp = res[1], V = 2u * Vp;
    ll invDelta = P - (ll)Vp;
    unsigned vrun = gv;
    for (int k = 0; k < WPW; ++k) {
      ull w64 = __shfl((long long)myword, k);
      ll p = ((w0 + k) << 6) + lane;
      bool invalid = !((w64 >> lane) & 1ull) && (p < P);
      if (invalid) {
        unsigned vb = vrun + (unsigned)__popcll(w64 & lt);
        ll posF = (ll)V + (p - (ll)vb);
        ll posR = posF + invDelta;
        int i, j;
        if (p < Pc) {
          decode_center(p, i, j);
        } else {
          ll q = p - Pc;
          i = (int)((q >> 10) & (N_ - 1));
          j = (int)(q & (N_ - 1));
        }
        float fi = (float)i, fj = (float)j;
        oi[posF] = fi; oj[posF] = fj;
        oi[posR] = fj; oj[posR] = fi;
      }
      vrun += (unsigned)__popcll(w64);
    }
  }
  __syncthreads();

  // ===== phase 2b: valid scatter for atom a = b (ssv reused from phase 1) =====
  {
    int a = b;
    unsigned mysum = 0;
    int m0 = 4 * tid;   // 256 threads x 4 atoms = all 1024 atoms
#pragma unroll
    for (int e = 0; e < 4; ++e) {
      int m = m0 + e;
      mysum += cntA[m] + cntB[m] + cntC[m] + cntD[m];
    }
    part[tid] = mysum;
    for (int off = 1; off < BLK; off <<= 1) {
      __syncthreads();
      unsigned x = (tid >= off) ? part[tid - off] : 0u;
      __syncthreads();
      part[tid] += x;
    }
    __syncthreads();
    if (tid == 0) {
      int q = a >> 2;
      unsigned excl = (q > 0) ? part[q - 1] : 0u;
      for (int m = 4 * q; m < a; ++m)
        excl += cntA[m] + cntB[m] + cntC[m] + cntD[m];
      unsigned sA = excl;
      unsigned sB = sA + cntA[a];
      unsigned sC = sB + cntB[a];
      unsigned sD = sC + cntC[a];
      res[0] = sA; res[1] = sB; res[2] = sC; res[3] = sD;
    }
    __syncthreads();
    if (wave == 0) {               // A: center forward, row (a, j>a), offset = 0 (fill)
      unsigned run = res[0];
      int len = N_ - 1 - a;
      if (len > 0) {
        ll rb = rowstart(a);
        ll wb = rb >> 6;
        int off = (int)(rb & 63);
        int nw = (int)(((ll)off + len - 1) >> 6) + 1;   // words spanned (<=17)
        ull myw = (lane < nw) ? mask64[wb + lane] : 0ull;
        int steps = (len + 63) >> 6;
        for (int k = 0; k < steps; ++k) {
          int idx = (k << 6) + lane;
          int t = off + idx;                 // bit position relative to wb
          ull wsel = (ull)__shfl((long long)myw, t >> 6);
          bool v = (idx < len) && ((wsel >> (t & 63)) & 1ull);
          ull bal = __ballot(v);
          if (v) {
            ll pos = (ll)(run + (unsigned)__popcll(bal & lt));
            oi[pos] = (float)a; oj[pos] = (float)(a + 1 + idx); ov[pos] = 1.f;
          }
          run += (unsigned)__popcll(bal);
        }
      }
    } else if (wave == 1) {        // B: shifted forward (s, a, j), offset = -sv[s]
      unsigned run = res[1];
      // word for (s,k) is (Pc>>6)+(s<<14)+(a<<4)+k ; bit index within word = lane.
      ll wbB = (Pc >> 6) + ((ll)a << 4);
      int nwB = S * 16;
      ull wB[4];
#pragma unroll
      for (int g = 0; g < 4; ++g) {
        int n = lane + (g << 6);
        wB[g] = (n < nwB) ? mask64[wbB + (((ll)(n >> 4)) << 14) + (n & 15)] : 0ull;
      }
      float ox = 0.f, oy = 0.f, oz = 0.f;
#pragma unroll
      for (int g = 0; g < 4; ++g) {
        int lim = nwB - (g << 6); if (lim > 64) lim = 64;
        for (int t = 0; t < lim; ++t) {
          int n = (g << 6) + t;
          if ((n & 15) == 0) {
            int s = n >> 4;
            ox = -ssv[s][0]; oy = -ssv[s][1]; oz = -ssv[s][2];
          }
          ull w64 = (ull)__shfl((long long)wB[g], t);   // == ballot (bit idx = lane)
          if ((w64 >> lane) & 1ull) {
            ll pos = (ll)(run + (unsigned)__popcll(w64 & lt));
            int j = ((n & 15) << 6) + lane;
            oi[pos] = (float)a; oj[pos] = (float)j; ov[pos] = 1.f;
            oo[3 * pos + 0] = ox; oo[3 * pos + 1] = oy; oo[3 * pos + 2] = oz;
          }
          run += (unsigned)__popcll(w64);
        }
      }
    } else if (wave == 2) {        // C: center reversed (i < a, a), offset = 0 (fill)
      unsigned run = res[2];
      int steps = (a + 63) >> 6;
      for (int kb = 0; kb < steps; kb += 8) {
        ull wC[8];
#pragma unroll
        for (int kk = 0; kk < 8; ++kk) {
          int i = ((kb + kk) << 6) + lane;
          wC[kk] = 0ull;
          if (kb + kk < steps && i < a) {
            ll b2 = rowstart(i) + (a - i - 1);
            wC[kk] = mask64[b2 >> 6];
          }
        }
#pragma unroll
        for (int kk = 0; kk < 8; ++kk) {
          int k = kb + kk;
          if (k >= steps) break;
          int i = (k << 6) + lane;
          bool v = false;
          if (i < a) {
            ll b2 = rowstart(i) + (a - i - 1);
            v = (wC[kk] >> (b2 & 63)) & 1ull;
          }
          ull bal = __ballot(v);
          if (v) {
            ll pos = (ll)(run + (unsigned)__popcll(bal & lt));
            oi[pos] = (float)a; oj[pos] = (float)i; ov[pos] = 1.f;
          }
          run += (unsigned)__popcll(bal);
        }
      }
    } else {                       // D: shifted reversed (s, i, a), offset = +sv[s]
      unsigned run = res[3];
      int abit = a & 63;
      for (int s = 0; s < S; ++s) {
        ll C0 = (Pc >> 6) + ((ll)s << 14) + (a >> 6);
        float ox = ssv[s][0], oy = ssv[s][1], oz = ssv[s][2];
#pragma unroll
        for (int kb = 0; kb < 16; kb += 8) {
          ull wD[8];
#pragma unroll
          for (int kk = 0; kk < 8; ++kk)
            wD[kk] = mask64[C0 + (((ll)(kb + kk)) << 10) + ((ll)lane << 4)];
#pragma unroll
          for (int kk = 0; kk < 8; ++kk) {
            bool v = (wD[kk] >> abit) & 1ull;
            ull bal = __ballot(v);
            if (v) {
              ll pos = (ll)(run + (unsigned)__popcll(bal & lt));
              int i = ((kb + kk) << 6) + lane;
              oi[pos] = (float)a; oj[pos] = (float)i; ov[pos] = 1.f;
              oo[3 * pos + 0] = ox; oo[3 * pos + 1] = oy; oo[3 * pos + 2] = oz;
            }
            run += (unsigned)__popcll(bal);
          }
        }
      }
    }
  }
}

static inline unsigned char* alignup(unsigned char* p, size_t a) {
  return (unsigned char*)(((uintptr_t)p + a - 1) & ~(uintptr_t)(a - 1));
}

extern "C" void kernel_launch(void* const* d_in, const int* in_sizes, int n_in,
                              void* d_out, int out_size, void* d_ws, size_t ws_size,
                              hipStream_t stream)
{
  const float* pos = (const float*)d_in[0];
  const float* box = (const float*)d_in[1];
  const int* shifts = (const int*)d_in[2];
  int S = in_sizes[2] / 3;                       // 13
  ll Pc = (ll)N_ * (N_ - 1) / 2;                 // 523776
  ll P = Pc + (ll)S * N_ * N_;                   // 14,155,264 (word-aligned)
  ll T = 2 * P;                                  // 28,310,528
  float* out = (float*)d_out;

  unsigned char* w = (unsigned char*)d_ws;
  ull* mask64 = (ull*)w;
  w += ((P + 63) / 64) * sizeof(ull);
  w = alignup(w, 256);
  unsigned* blockCount = (unsigned*)w; w += (size_t)NB * 4;
  w = alignup(w, 256);
  unsigned* cnt = (unsigned*)w;        w += (size_t)4 * N_ * 4;  // A,B,C,D contiguous

  float4* zp = (float4*)(out + 2 * T);

  void* args[] = { (void*)&pos, (void*)&box, (void*)&shifts, (void*)&S,
                   (void*)&Pc, (void*)&P, (void*)&T, (void*)&zp,
                   (void*)&mask64, (void*)&blockCount, (void*)&cnt, (void*)&out };
  hipLaunchCooperativeKernel((const void*)k_all, dim3(NB), dim3(BLK),
                             args, 0, stream);
}

// Round 10
// 703.064 us; speedup vs baseline: 1.4909x; 1.4909x over previous
//
#include <hip/hip_runtime.h>
#include <cstdint>

typedef long long ll;
typedef unsigned long long ull;

constexpr int N_ = 1024;           // atoms (fixed by problem)
constexpr int BLK = 256;
constexpr int NB  = 1024;          // classify / invalid-writer blocks (4/CU, 8/CU exact)
constexpr int RNDS = 54;           // rounds per classify block
constexpr int CHUNK = BLK * RNDS;  // 13824 pairs per block = 216 mask words
constexpr int WPW = 54;            // mask words per wave (invalid writer)
constexpr int Q4 = 27648;          // float4 zero-fill quota per classify block (T/NB)

__device__ __forceinline__ ll rowstart(int i) {
  return (ll)i * (2 * N_ - 1 - i) / 2;
}

// invert triu(N,k=1) linear index -> (i,j)
__device__ __forceinline__ void decode_center(ll p, int& i, int& j) {
  double disc = (double)(2 * N_ - 1) * (double)(2 * N_ - 1) - 8.0 * (double)p;
  int ii = (int)(((double)(2 * N_ - 1) - sqrt(disc)) * 0.5);
  if (ii < 0) ii = 0;
  if (ii > N_ - 2) ii = N_ - 2;
  while (rowstart(ii) > p) --ii;
  while (rowstart(ii + 1) <= p) ++ii;
  i = ii;
  j = ii + 1 + (int)(p - rowstart(ii));
}

// ---------------- kernel 1: classify pairs -> bitmask + counts, FUSED zero-fill of
// out[2T,6T) (offset+valid regions) as contiguous float4 streams overlapping the
// VALU classify work. 1024 blocks = exactly 4/CU (no co-residency imbalance tail).
// NOTE (R9): do NOT fuse into a cooperative kernel — grid.sync coherence on gfx950
// drops store throughput 6.3 -> 1.3 TB/s on the bulk write streams.
__global__ __launch_bounds__(BLK) void k_classify(
    const float* __restrict__ pos, const float* __restrict__ box,
    const int* __restrict__ shifts, int S, ll Pc, ll P, ll T4,
    float4* __restrict__ zp,
    ull* __restrict__ mask64, unsigned* __restrict__ blockCount,
    unsigned* __restrict__ cntA, unsigned* __restrict__ cntB,
    unsigned* __restrict__ cntC, unsigned* __restrict__ cntD)
{
  __shared__ float4 sp[N_];
  __shared__ float ssv[16][3];
  __shared__ unsigned wcnt[4];
  int tid = threadIdx.x;
  for (int a = tid; a < N_; a += BLK)
    sp[a] = make_float4(pos[3 * a + 0], pos[3 * a + 1], pos[3 * a + 2], 0.f);
  if (tid < S) {
    for (int k = 0; k < 3; ++k) {
      float acc = 0.f;
      for (int m = 0; m < 3; ++m)
        acc = __fadd_rn(acc, __fmul_rn((float)shifts[3 * tid + m], box[3 * m + k]));
      ssv[tid][k] = acc;
    }
  }
  __syncthreads();
  int lane = tid & 63, wave = tid >> 6;
  ll chunk = (ll)blockIdx.x * CHUNK;
  ll fillBase = (ll)blockIdx.x * Q4 + tid;
  const float4 z4 = make_float4(0.f, 0.f, 0.f, 0.f);
  unsigned wrun = 0;
  for (int r = 0; r < RNDS; ++r) {
    ll p0 = chunk + r * BLK + wave * 64;
    bool inr = (p0 < P);
    bool valid = false;
    if (inr) {
      ll p = p0 + lane;
      int i, j;
      float svx = 0.f, svy = 0.f, svz = 0.f;
      if (p < Pc) {
        decode_center(p, i, j);
      } else {
        ll q = p - Pc;
        int s = (int)(q >> 20);
        i = (int)((q >> 10) & (N_ - 1));
        j = (int)(q & (N_ - 1));
        svx = ssv[s][0]; svy = ssv[s][1]; svz = ssv[s][2];
      }
      float4 pi = sp[i], pj = sp[j];
      // strict IEEE order to match reference: (pi-pj)+sv, (x^2+y^2)+z^2, < 25.
      // d2 < 25.0f  <=>  rn(sqrt(d2)) < 5.0f  (sqrtf correctly rounded, monotone)
      float dx = __fadd_rn(__fsub_rn(pi.x, pj.x), svx);
      float dy = __fadd_rn(__fsub_rn(pi.y, pj.y), svy);
      float dz = __fadd_rn(__fsub_rn(pi.z, pj.z), svz);
      float d2 = __fadd_rn(__fadd_rn(__fmul_rn(dx, dx), __fmul_rn(dy, dy)),
                           __fmul_rn(dz, dz));
      valid = (d2 < 25.0f);
      if (valid) {
        if (p < Pc) { atomicAdd(&cntA[i], 1u); atomicAdd(&cntC[j], 1u); }
        else        { atomicAdd(&cntB[i], 1u); atomicAdd(&cntD[j], 1u); }
      }
    }
    ull bal = __ballot(valid);
    if (lane == 0) {
      if (inr) mask64[p0 >> 6] = bal;
      wrun += (unsigned)__popcll(bal);
    }
    // fused zero-fill: 2 float4 per thread per round, contiguous per block
    ll f0 = fillBase + ((ll)r << 9);
    if (f0 < T4) zp[f0] = z4;
    ll f1 = f0 + BLK;
    if (f1 < T4) zp[f1] = z4;
  }
  if (lane == 0) wcnt[wave] = wrun;
  __syncthreads();
  if (tid == 0)
    blockCount[blockIdx.x] = wcnt[0] + wcnt[1] + wcnt[2] + wcnt[3];
}

// ---------------- kernel 2: fused finisher. blocks [0,NB): invalid idx writer
// (p-indexed, per-wave 54-word span, ballot ranks); blocks [NB, NB+N_):
// valid scatter for atom a = blockIdx-NB, with PREFETCHED mask words so the
// rank walks are ALU-only. 2048 blocks = exactly 8/CU.
__global__ __launch_bounds__(BLK) void k_finish(
    const ull* __restrict__ mask64, const float* __restrict__ box,
    const int* __restrict__ shifts, int S, ll Pc, ll P, ll T,
    const unsigned* __restrict__ cntA, const unsigned* __restrict__ cntB,
    const unsigned* __restrict__ cntC, const unsigned* __restrict__ cntD,
    const unsigned* __restrict__ blockCount,
    float* __restrict__ out)
{
  __shared__ unsigned part[BLK];
  __shared__ unsigned res[8];
  __shared__ float ssv[16][3];
  __shared__ unsigned wq[4];
  int tid = threadIdx.x, lane = tid & 63, wave = tid >> 6;
  float* oi = out;
  float* oj = out + T;
  float* oo = out + 2 * T;
  float* ov = out + 5 * T;
  ull lt = (1ull << lane) - 1ull;

  if ((int)blockIdx.x < NB) {
    // ================= invalid writer =================
    int b = (int)blockIdx.x;
    unsigned mysum = 0;
    int e0 = 4 * tid;
#pragma unroll
    for (int e = 0; e < 4; ++e) mysum += blockCount[e0 + e];   // 256*4 = NB exact
    part[tid] = mysum;
    for (int off = 1; off < BLK; off <<= 1) {
      __syncthreads();
      unsigned x = (tid >= off) ? part[tid - off] : 0u;
      __syncthreads();
      part[tid] += x;
    }
    __syncthreads();
    if (tid == 0) {
      int q = b >> 2;
      unsigned excl = (q > 0) ? part[q - 1] : 0u;
      for (int m = 4 * q; m < b; ++m) excl += blockCount[m];
      res[0] = excl;            // valid count before this block
      res[1] = part[BLK - 1];   // Vp = total valid pair count
    }
    // per-wave span: 54 mask words, one per lane (lane<54)
    ll Wtot = P >> 6;           // P is word-aligned
    ll w0 = (ll)b * 216 + (ll)wave * WPW;
    ll widx = w0 + lane;
    ull myword = 0ull;
    if (lane < WPW) myword = (widx < Wtot) ? mask64[widx] : ~0ull; // fakes: no writes
    unsigned ws = (unsigned)__popcll(myword);
    for (int d = 1; d < 64; d <<= 1) ws += __shfl_xor(ws, d);
    if (lane == 0) wq[wave] = ws;
    __syncthreads();
    unsigned gv = res[0];
    for (int w2 = 0; w2 < 4; ++w2) if (w2 < wave) gv += wq[w2];
    unsigned Vp = res[1], V = 2u * Vp;
    ll invDelta = P - (ll)Vp;
    unsigned vrun = gv;
    for (int k = 0; k < WPW; ++k) {
      ull w64 = __shfl((long long)myword, k);
      ll p = ((w0 + k) << 6) + lane;
      bool invalid = !((w64 >> lane) & 1ull) && (p < P);
      if (invalid) {
        unsigned vb = vrun + (unsigned)__popcll(w64 & lt);
        ll posF = (ll)V + (p - (ll)vb);
        ll posR = posF + invDelta;
        int i, j;
        if (p < Pc) {
          decode_center(p, i, j);
        } else {
          ll q = p - Pc;
          i = (int)((q >> 10) & (N_ - 1));
          j = (int)(q & (N_ - 1));
        }
        float fi = (float)i, fj = (float)j;
        oi[posF] = fi; oj[posF] = fj;
        oi[posR] = fj; oj[posR] = fi;
      }
      vrun += (unsigned)__popcll(w64);
    }
  } else {
    // ================= valid scatter for atom a =================
    int a = (int)blockIdx.x - NB;
    if (tid < S) {
      for (int k = 0; k < 3; ++k) {
        float acc = 0.f;
        for (int m = 0; m < 3; ++m)
          acc = __fadd_rn(acc, __fmul_rn((float)shifts[3 * tid + m], box[3 * m + k]));
        ssv[tid][k] = acc;
      }
    }
    unsigned mysum = 0;
    int m0 = 4 * tid;   // 256 threads x 4 atoms = all 1024 atoms
#pragma unroll
    for (int e = 0; e < 4; ++e) {
      int m = m0 + e;
      mysum += cntA[m] + cntB[m] + cntC[m] + cntD[m];
    }
    part[tid] = mysum;
    for (int off = 1; off < BLK; off <<= 1) {
      __syncthreads();
      unsigned x = (tid >= off) ? part[tid - off] : 0u;
      __syncthreads();
      part[tid] += x;
    }
    __syncthreads();
    if (tid == 0) {
      int q = a >> 2;
      unsigned excl = (q > 0) ? part[q - 1] : 0u;
      for (int m = 4 * q; m < a; ++m)
        excl += cntA[m] + cntB[m] + cntC[m] + cntD[m];
      unsigned sA = excl;
      unsigned sB = sA + cntA[a];
      unsigned sC = sB + cntB[a];
      unsigned sD = sC + cntC[a];
      res[0] = sA; res[1] = sB; res[2] = sC; res[3] = sD;
    }
    __syncthreads();
    if (wave == 0) {               // A: center forward, row (a, j>a), offset = 0 (fill)
      unsigned run = res[0];
      int len = N_ - 1 - a;
      if (len > 0) {
        ll rb = rowstart(a);
        ll wb = rb >> 6;
        int off = (int)(rb & 63);
        int nw = (int)(((ll)off + len - 1) >> 6) + 1;   // words spanned (<=17)
        ull myw = (lane < nw) ? mask64[wb + lane] : 0ull;
        int steps = (len + 63) >> 6;
        for (int k = 0; k < steps; ++k) {
          int idx = (k << 6) + lane;
          int t = off + idx;                 // bit position relative to wb
          ull wsel = (ull)__shfl((long long)myw, t >> 6);
          bool v = (idx < len) && ((wsel >> (t & 63)) & 1ull);
          ull bal = __ballot(v);
          if (v) {
            ll pos = (ll)(run + (unsigned)__popcll(bal & lt));
            oi[pos] = (float)a; oj[pos] = (float)(a + 1 + idx); ov[pos] = 1.f;
          }
          run += (unsigned)__popcll(bal);
        }
      }
    } else if (wave == 1) {        // B: shifted forward (s, a, j), offset = -sv[s]
      unsigned run = res[1];
      // word for (s,k) is (Pc>>6)+(s<<14)+(a<<4)+k ; bit index within word = lane.
      // prefetch all S*16 (<=208) words: lane holds n = lane + 64*g, g<4.
      ll wbB = (Pc >> 6) + ((ll)a << 4);
      int nwB = S * 16;
      ull wB[4];
#pragma unroll
      for (int g = 0; g < 4; ++g) {
        int n = lane + (g << 6);
        wB[g] = (n < nwB) ? mask64[wbB + (((ll)(n >> 4)) << 14) + (n & 15)] : 0ull;
      }
      float ox = 0.f, oy = 0.f, oz = 0.f;
#pragma unroll
      for (int g = 0; g < 4; ++g) {
        int lim = nwB - (g << 6); if (lim > 64) lim = 64;
        for (int t = 0; t < lim; ++t) {
          int n = (g << 6) + t;
          if ((n & 15) == 0) {
            int s = n >> 4;
            ox = -ssv[s][0]; oy = -ssv[s][1]; oz = -ssv[s][2];
          }
          ull w64 = (ull)__shfl((long long)wB[g], t);   // == ballot (bit idx = lane)
          if ((w64 >> lane) & 1ull) {
            ll pos = (ll)(run + (unsigned)__popcll(w64 & lt));
            int j = ((n & 15) << 6) + lane;
            oi[pos] = (float)a; oj[pos] = (float)j; ov[pos] = 1.f;
            oo[3 * pos + 0] = ox; oo[3 * pos + 1] = oy; oo[3 * pos + 2] = oz;
          }
          run += (unsigned)__popcll(w64);
        }
      }
    } else if (wave == 2) {        // C: center reversed (i < a, a), offset = 0 (fill)
      unsigned run = res[2];
      int steps = (a + 63) >> 6;
      for (int kb = 0; kb < steps; kb += 8) {
        ull wC[8];
#pragma unroll
        for (int kk = 0; kk < 8; ++kk) {
          int i = ((kb + kk) << 6) + lane;
          wC[kk] = 0ull;
          if (kb + kk < steps && i < a) {
            ll b2 = rowstart(i) + (a - i - 1);
            wC[kk] = mask64[b2 >> 6];
          }
        }
#pragma unroll
        for (int kk = 0; kk < 8; ++kk) {
          int k = kb + kk;
          if (k >= steps) break;
          int i = (k << 6) + lane;
          bool v = false;
          if (i < a) {
            ll b2 = rowstart(i) + (a - i - 1);
            v = (wC[kk] >> (b2 & 63)) & 1ull;
          }
          ull bal = __ballot(v);
          if (v) {
            ll pos = (ll)(run + (unsigned)__popcll(bal & lt));
            oi[pos] = (float)a; oj[pos] = (float)i; ov[pos] = 1.f;
          }
          run += (unsigned)__popcll(bal);
        }
      }
    } else {                       // D: shifted reversed (s, i, a), offset = +sv[s]
      unsigned run = res[3];
      int abit = a & 63;
      for (int s = 0; s < S; ++s) {
        ll C0 = (Pc >> 6) + ((ll)s << 14) + (a >> 6);
        float ox = ssv[s][0], oy = ssv[s][1], oz = ssv[s][2];
#pragma unroll
        for (int kb = 0; kb < 16; kb += 8) {
          ull wD[8];
#pragma unroll
          for (int kk = 0; kk < 8; ++kk)
            wD[kk] = mask64[C0 + (((ll)(kb + kk)) << 10) + ((ll)lane << 4)];
#pragma unroll
          for (int kk = 0; kk < 8; ++kk) {
            bool v = (wD[kk] >> abit) & 1ull;
            ull bal = __ballot(v);
            if (v) {
              ll pos = (ll)(run + (unsigned)__popcll(bal & lt));
              int i = ((kb + kk) << 6) + lane;
              oi[pos] = (float)a; oj[pos] = (float)i; ov[pos] = 1.f;
              oo[3 * pos + 0] = ox; oo[3 * pos + 1] = oy; oo[3 * pos + 2] = oz;
            }
            run += (unsigned)__popcll(bal);
          }
        }
      }
    }
  }
}

static inline unsigned char* alignup(unsigned char* p, size_t a) {
  return (unsigned char*)(((uintptr_t)p + a - 1) & ~(uintptr_t)(a - 1));
}

extern "C" void kernel_launch(void* const* d_in, const int* in_sizes, int n_in,
                              void* d_out, int out_size, void* d_ws, size_t ws_size,
                              hipStream_t stream)
{
  const float* pos = (const float*)d_in[0];
  const float* box = (const float*)d_in[1];
  const int* shifts = (const int*)d_in[2];
  int S = in_sizes[2] / 3;                       // 13
  ll Pc = (ll)N_ * (N_ - 1) / 2;                 // 523776
  ll P = Pc + (ll)S * N_ * N_;                   // 14,155,264 (word-aligned)
  ll T = 2 * P;                                  // 28,310,528
  ll T4 = T;                                     // float4 count of region [2T,6T)
  float* out = (float*)d_out;

  unsigned char* w = (unsigned char*)d_ws;
  ull* mask64 = (ull*)w;
  w += ((P + 63) / 64) * sizeof(ull);
  w = alignup(w, 256);
  unsigned* blockCount = (unsigned*)w; w += (size_t)NB * 4;
  w = alignup(w, 256);
  unsigned* cnt = (unsigned*)w;        w += (size_t)4 * N_ * 4;  // A,B,C,D contiguous
  unsigned* cntA = cnt, *cntB = cnt + N_, *cntC = cnt + 2 * N_, *cntD = cnt + 3 * N_;

  // zero only the tiny atomic counters (16 KB); out[2T,6T) zero-fill is fused
  // into k_classify (overlaps its VALU work), idx regions come from k_finish.
  hipMemsetAsync(cnt, 0, (size_t)4 * N_ * sizeof(unsigned), stream);

  k_classify<<<NB, BLK, 0, stream>>>(pos, box, shifts, S, Pc, P, T4,
                                     (float4*)(out + 2 * T),
                                     mask64, blockCount, cntA, cntB, cntC, cntD);
  k_finish<<<NB + N_, BLK, 0, stream>>>(mask64, box, shifts, S, Pc, P, T,
                                        cntA, cntB, cntC, cntD, blockCount, out);
}